// Round 1
// baseline (95.094 us; speedup 1.0000x reference)
//
#include <hip/hip_runtime.h>

#define B_      2
#define C_      256
#define H_      96
#define W_      96
#define HW_     (H_ * W_)
#define P_      7
#define PP_     (P_ * P_)
#define NROIS_  512
#define SCALE_  0.0625f
#define TSTD_   0.1f

#define NGROUP_ 8                       // channel groups
#define GC_     (C_ / NGROUP_)          // 32 channels per group

#define TPB2_   448                     // pass-2 block: 56 bin slots x 8 lanes (49 active bins)

typedef float vf4 __attribute__((ext_vector_type(4)));
typedef float vf2 __attribute__((ext_vector_type(2)));

// f32 -> bf16 (round-to-nearest-even), as raw bits
__device__ __forceinline__ unsigned f2bf(float f) {
    union { float f; unsigned u; } x; x.f = f;
    return (x.u + 0x7fffu + ((x.u >> 16) & 1u)) >> 16;
}
// packed-bf16 word -> float2 {low ushort, high ushort}
__device__ __forceinline__ vf2 bfpair(unsigned u) {
    union { unsigned i; float f; } lo, hi;
    lo.i = u << 16; hi.i = u & 0xffff0000u;
    vf2 r; r.x = lo.f; r.y = hi.f; return r;
}

// ---------------------------------------------------------------------------
// Pass 1: f32 CHW -> bf16 group-planar [b][g][HW][32ch].
// Unchanged from R6 except: zero ONE pad pixel (64 B) past the buffer end.
// Pass 2's x-pair loads may touch pixel (x0+1) at the very end of the last
// plane with weight exactly 0 — poisoned workspace bytes there could be NaN
// and NaN*0 would corrupt; a zeroed pad makes it exact.
// ---------------------------------------------------------------------------
__global__ __launch_bounds__(256) void nchw_to_gp_bf16(const float* __restrict__ in,
                                                       ushort* __restrict__ out) {
    __shared__ float tile[32][36];          // [ch][px], stride 36: b128-aligned
    const int b   = blockIdx.z;
    const int g   = blockIdx.x & (NGROUP_ - 1);
    const int p0  = (blockIdx.x >> 3) * 32; // pixel tile origin
    const int c0  = g * 32;                 // channel tile origin
    const int tid = threadIdx.x;

    if (blockIdx.x == 0 && blockIdx.z == 0 && tid < 32)
        out[(size_t)B_ * NGROUP_ * HW_ * GC_ + tid] = (ushort)0;   // pad pixel

    const float* src = in + (size_t)b * (C_ * HW_);
    ushort*      dst = out + ((size_t)(b * NGROUP_ + g) * HW_) * GC_;

    // read: lane = (ch row, px quad); one vf4 per thread covers 32x32
    {
        const int cr = tid >> 3;            // 0..31 channel row
        const int pq = (tid & 7) * 4;       // pixel quad
        const vf4 v = __builtin_nontemporal_load(
            (const vf4*)&src[(size_t)(c0 + cr) * HW_ + p0 + pq]);
        *(vf4*)&tile[cr][pq] = v;
    }
    __syncthreads();

    // write: lane = (px, ch quad); pack 4 ch -> uint2, coalesced
    {
        const int p  = tid >> 3;            // 0..31 pixel
        const int cq = (tid & 7) * 4;       // channel quad
        uint2 o;
        o.x = f2bf(tile[cq + 0][p]) | (f2bf(tile[cq + 1][p]) << 16);
        o.y = f2bf(tile[cq + 2][p]) | (f2bf(tile[cq + 3][p]) << 16);
        *(uint2*)&((unsigned*)dst)[(size_t)(p0 + p) * (GC_ / 2) + (cq >> 1)] = o;
    }
}

// ---------------------------------------------------------------------------
// Pass 2 (R7 restructure): 8 lanes/bin, x-corner-PAIR loads.
// The two x-corners of a bilinear sample are pixels x0 and x0+1 = 128
// contiguous bytes (when ceil(wc)==floor(wc) the hi-x weight dx is exactly 0,
// so unconditionally loading x0+1 is still exact).  8 lanes x 16 B cover the
// pair in ONE instruction: per-thread gathers 16 -> 8, per-wave address
// pattern becomes 8-lane/128 B contiguous runs (TA merge), v[] 64 -> 32
// VGPRs.  Lane q: px = q>>2 selects the x0/x0+1 half, (q&3)*8 the channels;
// x0/x1 partial sums combine with one __shfl_xor(.,4) at the end.
// __launch_bounds__(448,6): VGPR cap 85 -> 3 blocks/CU = 21 waves/CU
// (vs 16 before).  trans reads staged via LDS (kills the duplicated scatter).
// ---------------------------------------------------------------------------
__global__ __launch_bounds__(TPB2_, 6) void dpsroi_pool7(const ushort* __restrict__ feat,
                                                         const float* __restrict__ rois,
                                                         const float* __restrict__ trans,
                                                         float* __restrict__ out) {
    __shared__ float sout[GC_ * PP_];       // 32*49*4 = 6272 B, global layout
    __shared__ float ttab[2 * PP_];         // staged trans for this roi

    const int blk = blockIdx.x;
    const int g   = blk & (NGROUP_ - 1);    // static XCD affinity
    const int n   = blk >> 3;
    const int tid = threadIdx.x;
    const int bin = tid >> 3;               // 0..55 (49 active)
    const int q   = tid & 7;                // lane-in-bin
    const int px  = q >> 2;                 // 0: x0 pixel, 1: x0+1 pixel
    const int ch0 = (q & 3) * 8;            // 8 channels per lane

    if (tid < 2 * PP_) ttab[tid] = trans[n * (2 * PP_) + tid];

    // ROI geometry (block-uniform -> scalar regs)
    const int   broi = (int)rois[n * 5 + 0];
    const float x1 = rintf(rois[n * 5 + 1]) * SCALE_ - 0.5f;
    const float y1 = rintf(rois[n * 5 + 2]) * SCALE_ - 0.5f;
    const float x2 = (rintf(rois[n * 5 + 3]) + 1.0f) * SCALE_ - 0.5f;
    const float y2 = (rintf(rois[n * 5 + 4]) + 1.0f) * SCALE_ - 0.5f;
    const float rw = fmaxf(x2 - x1, 0.1f);
    const float rh = fmaxf(y2 - y1, 0.1f);
    const float bin_w = rw * (1.0f / 7.0f);
    const float bin_h = rh * (1.0f / 7.0f);
    const float sub_w = bin_w * 0.5f;
    const float sub_h = bin_h * 0.5f;

    __syncthreads();                        // ttab ready

    const ushort* fb = feat + ((size_t)(broi * NGROUP_ + g) * HW_) * GC_ + q * 8;

    if (bin < PP_) {
        const int pi = bin / P_;
        const int pj = bin - pi * P_;
        const float tx = ttab[bin] * TSTD_;
        const float ty = ttab[PP_ + bin] * TSTD_;
        const float wstart = (float)pj * bin_w + x1 + tx * rw;
        const float hstart = (float)pi * bin_h + y1 + ty * rh;

        // ---- phase 1: 8 weights + 8 row offsets (this lane's x-side only) ----
        float wt[8];
        int   ofs[8];
        int   cnt = 0;
#pragma unroll
        for (int s = 0; s < 4; ++s) {
            const float w = wstart + (float)(s & 1) * sub_w;
            const float h = hstart + (float)(s >> 1) * sub_h;
            const bool valid = (w >= -0.5f) & (w <= (float)W_ - 0.5f) &
                               (h >= -0.5f) & (h <= (float)H_ - 0.5f);
            cnt += valid ? 1 : 0;
            const float vf = valid ? 1.0f : 0.0f;
            const float wc  = fminf(fmaxf(w, 0.0f), (float)(W_ - 1));
            const float hc  = fminf(fmaxf(h, 0.0f), (float)(H_ - 1));
            const float x0f = floorf(wc), y0f = floorf(hc);
            const float dx  = wc - x0f,   dy  = hc - y0f;
            const int   x0  = (int)x0f,   y0  = (int)y0f;
            const int   yp  = (int)ceilf(hc);
            const float wx  = vf * (px ? dx : (1.0f - dx));
            wt[2 * s + 0] = wx * (1.0f - dy);
            wt[2 * s + 1] = wx * dy;
            ofs[2 * s + 0] = y0 * W_ + x0;      // row y0, pixel pair (x0, x0+1)
            ofs[2 * s + 1] = yp * W_ + x0;      // row y1
        }

        // ---- phase 2: 8 pair-gathers in flight (128 B per bin per load) ----
        uint4 v[8];
#pragma unroll
        for (int i = 0; i < 8; ++i)
            v[i] = *(const uint4*)(fb + (size_t)ofs[i] * GC_);

        // ---- phase 3: packed unpack + FMA ----
        vf2 a01 = {0.f, 0.f}, a23 = {0.f, 0.f}, a45 = {0.f, 0.f}, a67 = {0.f, 0.f};
#pragma unroll
        for (int i = 0; i < 8; ++i) {
            vf2 w2; w2.x = wt[i]; w2.y = wt[i];
            a01 = __builtin_elementwise_fma(w2, bfpair(v[i].x), a01);
            a23 = __builtin_elementwise_fma(w2, bfpair(v[i].y), a23);
            a45 = __builtin_elementwise_fma(w2, bfpair(v[i].z), a45);
            a67 = __builtin_elementwise_fma(w2, bfpair(v[i].w), a67);
        }

        // ---- combine x0/x1 partials across lane pairs (q <-> q^4) ----
        float a[8] = { a01.x, a01.y, a23.x, a23.y, a45.x, a45.y, a67.x, a67.y };
        const float inv = (cnt > 0) ? (1.0f / (float)cnt) : 0.0f;
#pragma unroll
        for (int j = 0; j < 8; ++j) {
            const float s2 = a[j] + __shfl_xor(a[j], 4);
            if (px == 0)
                sout[(ch0 + j) * PP_ + bin] = s2 * inv;
        }
    }

    __syncthreads();
    // out[n, g*32 : (g+1)*32, :, :] contiguous: 32*49 = 1568 floats
    float* outn = out + ((size_t)n * C_ + g * GC_) * PP_;
    for (int f = tid; f < GC_ * PP_; f += TPB2_)
        __builtin_nontemporal_store(sout[f], &outn[f]);
}

extern "C" void kernel_launch(void* const* d_in, const int* in_sizes, int n_in,
                              void* d_out, int out_size, void* d_ws, size_t ws_size,
                              hipStream_t stream) {
    const float* feat  = (const float*)d_in[0];   // (2,256,96,96) f32
    const float* rois  = (const float*)d_in[1];   // (512,5)
    const float* trans = (const float*)d_in[2];   // (512,2,7,7)
    float* out = (float*)d_out;                   // (512,256,7,7) f32

    ushort* gp = (ushort*)d_ws;                   // bf16 group-planar, 9.4 MB (+64 B pad)
    dim3 tb(256);
    dim3 tg((HW_ / 32) * NGROUP_, 1, B_);         // g = blockIdx.x & 7
    nchw_to_gp_bf16<<<tg, tb, 0, stream>>>(feat, gp);
    dpsroi_pool7<<<NROIS_ * NGROUP_, TPB2_, 0, stream>>>(gp, rois, trans, out);
}